// Round 1
// baseline (664.494 us; speedup 1.0000x reference)
//
#include <hip/hip_runtime.h>
#include <hip/hip_bf16.h>

#define NN 100000
#define NE 1600000
constexpr int NB1 = (NN + 1023) / 1024;  // 98 scan blocks

// ---------------- edge dtype detection ----------------
// int64 edge data (values < 2^32) => every odd 32-bit word of the buffer is 0.
// Real int32 index data has random values at odd positions. flag=1 => int64.
__global__ void k_detect_i64(const unsigned* __restrict__ ei, int* __restrict__ flag) {
    __shared__ int any_nz;
    if (threadIdx.x == 0) any_nz = 0;
    __syncthreads();
    int nz = 0;
    for (int i = threadIdx.x; i < 2048; i += 256)
        if (ei[2 * i + 1] != 0u) nz = 1;
    if (nz) atomicExch(&any_nz, 1);
    __syncthreads();
    if (threadIdx.x == 0) *flag = (any_nz == 0) ? 1 : 0;
}

__device__ __forceinline__ int edge_at(const void* ei, int is64, long long idx) {
    if (is64) return (int)((const long long*)ei)[idx];
    return ((const int*)ei)[idx];
}

// ---------------- graph prep ----------------
__global__ void k_init_deg(int* __restrict__ deg) {
    int v = blockIdx.x * 256 + threadIdx.x;
    if (v < NN) deg[v] = 1;  // self loop
}

__global__ void k_hist(const void* __restrict__ ei, const int* __restrict__ flag,
                       int* __restrict__ deg) {
    int is64 = *flag;
    int stride = gridDim.x * blockDim.x;
    for (int e = blockIdx.x * blockDim.x + threadIdx.x; e < NE; e += stride) {
        int d = edge_at(ei, is64, (long long)NE + e);
        if ((unsigned)d < NN) atomicAdd(&deg[d], 1);
    }
}

__global__ void k_dinv(const int* __restrict__ deg, float* __restrict__ dinv) {
    int v = blockIdx.x * 256 + threadIdx.x;
    if (v < NN) dinv[v] = rsqrtf((float)deg[v]);
}

// exclusive scan of (deg-1) -> row_off, 1024 elems/block
__global__ void k_scan1(const int* __restrict__ deg, int* __restrict__ row_off,
                        int* __restrict__ bsum) {
    __shared__ int lds[256];
    int t = threadIdx.x, b = blockIdx.x;
    int base = b * 1024 + t * 4;
    int v0 = (base + 0 < NN) ? deg[base + 0] - 1 : 0;
    int v1 = (base + 1 < NN) ? deg[base + 1] - 1 : 0;
    int v2 = (base + 2 < NN) ? deg[base + 2] - 1 : 0;
    int v3 = (base + 3 < NN) ? deg[base + 3] - 1 : 0;
    lds[t] = v0 + v1 + v2 + v3;
    __syncthreads();
    for (int off = 1; off < 256; off <<= 1) {
        int x = (t >= off) ? lds[t - off] : 0;
        __syncthreads();
        lds[t] += x;
        __syncthreads();
    }
    int excl = (t > 0) ? lds[t - 1] : 0;
    if (t == 255) bsum[b] = lds[255];
    if (base + 0 < NN) row_off[base + 0] = excl;
    if (base + 1 < NN) row_off[base + 1] = excl + v0;
    if (base + 2 < NN) row_off[base + 2] = excl + v0 + v1;
    if (base + 3 < NN) row_off[base + 3] = excl + v0 + v1 + v2;
}

__global__ void k_scan2(int* __restrict__ bsum) {
    __shared__ int lds[128];
    int t = threadIdx.x;
    int v = (t < NB1) ? bsum[t] : 0;
    lds[t] = v;
    __syncthreads();
    for (int off = 1; off < 128; off <<= 1) {
        int x = (t >= off) ? lds[t - off] : 0;
        __syncthreads();
        lds[t] += x;
        __syncthreads();
    }
    if (t < NB1) bsum[t] = lds[t] - v;  // exclusive
}

__global__ void k_scan3(int* __restrict__ row_off, const int* __restrict__ bsum,
                        int* __restrict__ cursor) {
    int v = blockIdx.x * 256 + threadIdx.x;
    if (v < NN) {
        int r = row_off[v] + bsum[v >> 10];
        row_off[v] = r;
        cursor[v] = r;
    } else if (v == NN) {
        row_off[NN] = NE;
    }
}

__global__ void k_scatter(const void* __restrict__ ei, const int* __restrict__ flag,
                          int* __restrict__ cursor, int* __restrict__ csr) {
    int is64 = *flag;
    int stride = gridDim.x * blockDim.x;
    for (int e = blockIdx.x * blockDim.x + threadIdx.x; e < NE; e += stride) {
        int s = edge_at(ei, is64, e);
        int d = edge_at(ei, is64, (long long)NE + e);
        if ((unsigned)s < NN && (unsigned)d < NN) {
            int pos = atomicAdd(&cursor[d], 1);
            csr[pos] = s;
        }
    }
}

// ---------------- GEMM: H[n,:] = dinv[n] * (X[n,:] @ W) ----------------
// W fully in LDS, X in 32-row LDS tiles, thread computes TR rows x 4 cols.
template <int C>
__global__ __launch_bounds__(256, 2) void k_gemm(const float* __restrict__ X,
                                                 const float* __restrict__ W,
                                                 const float* __restrict__ dinv,
                                                 float* __restrict__ H) {
    constexpr int K = 128, R = 32;
    constexpr int COLG = C / 4;          // col groups (float4)
    constexpr int TR = R / (256 / COLG); // rows per thread: 4 (C=128), 2 (C=64)
    __shared__ float ws[K * C];
    __shared__ float xs[R * K];
    const int tid = threadIdx.x;
    for (int i = tid; i < K * C / 4; i += 256)
        ((float4*)ws)[i] = ((const float4*)W)[i];
    const int cg = tid % COLG;
    const int rs = tid / COLG;
    constexpr int NTILES = NN / R;  // 3125 exactly
    for (int tile = blockIdx.x; tile < NTILES; tile += gridDim.x) {
        const int row0 = tile * R;
        __syncthreads();  // xs reuse guard (also covers ws load on iter 0)
        for (int i = tid; i < R * K / 4; i += 256)
            ((float4*)xs)[i] = ((const float4*)(X + (size_t)row0 * K))[i];
        __syncthreads();
        float4 acc[TR];
#pragma unroll
        for (int r = 0; r < TR; r++) acc[r] = make_float4(0.f, 0.f, 0.f, 0.f);
#pragma unroll 2
        for (int k0 = 0; k0 < K; k0 += 4) {
            float4 xv[TR];
#pragma unroll
            for (int r = 0; r < TR; r++)
                xv[r] = *(const float4*)&xs[(rs * TR + r) * K + k0];
#pragma unroll
            for (int kk = 0; kk < 4; kk++) {
                float4 w = *(const float4*)&ws[(k0 + kk) * C + cg * 4];
#pragma unroll
                for (int r = 0; r < TR; r++) {
                    float xr = (kk == 0) ? xv[r].x : (kk == 1) ? xv[r].y
                             : (kk == 2) ? xv[r].z : xv[r].w;
                    acc[r].x = fmaf(xr, w.x, acc[r].x);
                    acc[r].y = fmaf(xr, w.y, acc[r].y);
                    acc[r].z = fmaf(xr, w.z, acc[r].z);
                    acc[r].w = fmaf(xr, w.w, acc[r].w);
                }
            }
        }
#pragma unroll
        for (int r = 0; r < TR; r++) {
            int row = row0 + rs * TR + r;
            float dv = dinv[row];
            float4 o;
            o.x = acc[r].x * dv; o.y = acc[r].y * dv;
            o.z = acc[r].z * dv; o.w = acc[r].w * dv;
            *(float4*)&H[(size_t)row * C + cg * 4] = o;
        }
    }
}

// ---------------- Aggregation: OUT[v] = relu(dinv[v]*(sum_in H[u] + H[v]) + b) ----------------
// One wave per node; lane covers C/64 contiguous floats.
template <int C, bool RELU>
__global__ __launch_bounds__(256) void k_agg(const float* __restrict__ H,
                                             const int* __restrict__ row_off,
                                             const int* __restrict__ csr,
                                             const float* __restrict__ dinv,
                                             const float* __restrict__ bias,
                                             float* __restrict__ OUT) {
    const int lane = threadIdx.x & 63;
    const int node = blockIdx.x * 4 + (threadIdx.x >> 6);
    if (node >= NN) return;
    const int beg = row_off[node];
    const int end = row_off[node + 1];
    if constexpr (C == 128) {
        const float2* __restrict__ Hp = (const float2*)H;
        const int c2 = lane;  // float2 column index
        float ax = 0.f, ay = 0.f;
        int j = beg;
        for (; j + 4 <= end; j += 4) {
            int s0 = csr[j], s1 = csr[j + 1], s2 = csr[j + 2], s3 = csr[j + 3];
            float2 a = Hp[(size_t)s0 * 64 + c2];
            float2 b = Hp[(size_t)s1 * 64 + c2];
            float2 c = Hp[(size_t)s2 * 64 + c2];
            float2 d = Hp[(size_t)s3 * 64 + c2];
            ax += (a.x + b.x) + (c.x + d.x);
            ay += (a.y + b.y) + (c.y + d.y);
        }
        for (; j < end; ++j) {
            int s = csr[j];
            float2 a = Hp[(size_t)s * 64 + c2];
            ax += a.x; ay += a.y;
        }
        float2 hv = Hp[(size_t)node * 64 + c2];
        ax += hv.x; ay += hv.y;
        float dv = dinv[node];
        float2 bb = ((const float2*)bias)[c2];
        float ox = fmaf(ax, dv, bb.x);
        float oy = fmaf(ay, dv, bb.y);
        if (RELU) { ox = fmaxf(ox, 0.f); oy = fmaxf(oy, 0.f); }
        float2 o; o.x = ox; o.y = oy;
        ((float2*)OUT)[(size_t)node * 64 + c2] = o;
    } else {  // C == 64
        const int c = lane;
        float ax = 0.f;
        int j = beg;
        for (; j + 4 <= end; j += 4) {
            int s0 = csr[j], s1 = csr[j + 1], s2 = csr[j + 2], s3 = csr[j + 3];
            float a = H[(size_t)s0 * 64 + c];
            float b = H[(size_t)s1 * 64 + c];
            float c4 = H[(size_t)s2 * 64 + c];
            float d = H[(size_t)s3 * 64 + c];
            ax += (a + b) + (c4 + d);
        }
        for (; j < end; ++j) ax += H[(size_t)csr[j] * 64 + c];
        ax += H[(size_t)node * 64 + c];
        float dv = dinv[node];
        float o = fmaf(ax, dv, bias[c]);
        if (RELU) o = fmaxf(o, 0.f);
        OUT[(size_t)node * 64 + c] = o;
    }
}

extern "C" void kernel_launch(void* const* d_in, const int* in_sizes, int n_in,
                              void* d_out, int out_size, void* d_ws, size_t ws_size,
                              hipStream_t stream) {
    const float* x  = (const float*)d_in[0];
    const void*  ei = d_in[1];
    const float* W1 = (const float*)d_in[2];
    const float* b1 = (const float*)d_in[3];
    const float* W2 = (const float*)d_in[4];
    const float* b2 = (const float*)d_in[5];
    const float* W3 = (const float*)d_in[6];
    const float* b3 = (const float*)d_in[7];
    float* out = (float*)d_out;

    char* wsp = (char*)d_ws;
    size_t off = 0;
    auto alloc = [&](size_t bytes) -> void* {
        void* p = wsp + off;
        off += (bytes + 255) & ~(size_t)255;
        return p;
    };
    float* A       = (float*)alloc((size_t)NN * 128 * 4);
    float* B       = (float*)alloc((size_t)NN * 128 * 4);
    int*   deg     = (int*)alloc((size_t)NN * 4);
    float* dinv    = (float*)alloc((size_t)NN * 4);
    int*   row_off = (int*)alloc(((size_t)NN + 1) * 4);
    int*   cursor  = (int*)alloc((size_t)NN * 4);
    int*   bsum    = (int*)alloc((size_t)NB1 * 4);
    int*   csr     = (int*)alloc((size_t)NE * 4);
    int*   flag    = (int*)alloc(256);
    if (off > ws_size) return;  // workspace too small: fail loudly (wrong output)

    k_detect_i64<<<1, 256, 0, stream>>>((const unsigned*)ei, flag);
    k_init_deg<<<(NN + 255) / 256, 256, 0, stream>>>(deg);
    k_hist<<<1024, 256, 0, stream>>>(ei, flag, deg);
    k_dinv<<<(NN + 255) / 256, 256, 0, stream>>>(deg, dinv);
    k_scan1<<<NB1, 256, 0, stream>>>(deg, row_off, bsum);
    k_scan2<<<1, 128, 0, stream>>>(bsum);
    k_scan3<<<(NN + 1 + 255) / 256, 256, 0, stream>>>(row_off, bsum, cursor);
    k_scatter<<<1024, 256, 0, stream>>>(ei, flag, cursor, csr);

    k_gemm<128><<<512, 256, 0, stream>>>(x, W1, dinv, A);
    k_agg<128, true><<<NN / 4, 256, 0, stream>>>(A, row_off, csr, dinv, b1, B);
    k_gemm<128><<<512, 256, 0, stream>>>(B, W2, dinv, A);
    k_agg<128, true><<<NN / 4, 256, 0, stream>>>(A, row_off, csr, dinv, b2, B);
    k_gemm<64><<<512, 256, 0, stream>>>(B, W3, dinv, A);
    k_agg<64, false><<<NN / 4, 256, 0, stream>>>(A, row_off, csr, dinv, b3, out);
}

// Round 2
// 618.994 us; speedup vs baseline: 1.0735x; 1.0735x over previous
//
#include <hip/hip_runtime.h>
#include <hip/hip_bf16.h>

#define NN 100000
#define NE 1600000
constexpr int NB1 = (NN + 1023) / 1024;  // 98 scan blocks
constexpr int NBUK = (NN + 255) / 256;   // 391 buckets of 256 nodes
constexpr int KSUB = 8;                  // sub-segments per bucket
constexpr int CAPSUB = 1024;             // capacity per sub-segment (mean 512, 22 sigma headroom)
constexpr int CNT_PAD = 16;              // ints per counter (own cache line)

// ---------------- edge dtype detection ----------------
// int64 edge data (values < 2^32) => every odd 32-bit word of the buffer is 0.
__global__ void k_detect_i64(const unsigned* __restrict__ ei, int* __restrict__ flag) {
    __shared__ int any_nz;
    if (threadIdx.x == 0) any_nz = 0;
    __syncthreads();
    int nz = 0;
    for (int i = threadIdx.x; i < 2048; i += 256)
        if (ei[2 * i + 1] != 0u) nz = 1;
    if (nz) atomicExch(&any_nz, 1);
    __syncthreads();
    if (threadIdx.x == 0) *flag = (any_nz == 0) ? 1 : 0;
}

__device__ __forceinline__ int edge_at(const void* ei, int is64, long long idx) {
    if (is64) return (int)((const long long*)ei)[idx];
    return ((const int*)ei)[idx];
}

// ---------------- graph prep ----------------
__global__ void k_init(int* __restrict__ deg, int* __restrict__ bcnt) {
    int v = blockIdx.x * 256 + threadIdx.x;
    if (v < NN) deg[v] = 1;  // self loop
    if (v < NBUK * KSUB) bcnt[v * CNT_PAD] = 0;
}

// One pass over edges: degree histogram + bucketed append of packed edge records.
__global__ void k_phaseA(const void* __restrict__ ei, const int* __restrict__ flag,
                         int* __restrict__ deg, int* __restrict__ bcnt,
                         unsigned* __restrict__ staging) {
    const int is64 = *flag;
    const int k = blockIdx.x & (KSUB - 1);
    const int stride = gridDim.x * blockDim.x;
    for (int e = blockIdx.x * blockDim.x + threadIdx.x; e < NE; e += stride) {
        int s = edge_at(ei, is64, e);
        int d = edge_at(ei, is64, (long long)NE + e);
        if ((unsigned)s < NN && (unsigned)d < NN) {
            atomicAdd(&deg[d], 1);
            int b = d >> 8;
            int intra = atomicAdd(&bcnt[(b * KSUB + k) * CNT_PAD], 1);
            if (intra < CAPSUB)  // statistically impossible to overflow; guard vs corruption
                staging[(size_t)b * (KSUB * CAPSUB) + k * CAPSUB + intra] =
                    (unsigned)s | ((unsigned)(d & 255) << 17);
        }
    }
}

__global__ void k_dinv(const int* __restrict__ deg, float* __restrict__ dinv) {
    int v = blockIdx.x * 256 + threadIdx.x;
    if (v < NN) dinv[v] = rsqrtf((float)deg[v]);
}

// exclusive scan of (deg-1) -> row_off, 1024 elems/block
__global__ void k_scan1(const int* __restrict__ deg, int* __restrict__ row_off,
                        int* __restrict__ bsum) {
    __shared__ int lds[256];
    int t = threadIdx.x, b = blockIdx.x;
    int base = b * 1024 + t * 4;
    int v0 = (base + 0 < NN) ? deg[base + 0] - 1 : 0;
    int v1 = (base + 1 < NN) ? deg[base + 1] - 1 : 0;
    int v2 = (base + 2 < NN) ? deg[base + 2] - 1 : 0;
    int v3 = (base + 3 < NN) ? deg[base + 3] - 1 : 0;
    lds[t] = v0 + v1 + v2 + v3;
    __syncthreads();
    for (int off = 1; off < 256; off <<= 1) {
        int x = (t >= off) ? lds[t - off] : 0;
        __syncthreads();
        lds[t] += x;
        __syncthreads();
    }
    int excl = (t > 0) ? lds[t - 1] : 0;
    if (t == 255) bsum[b] = lds[255];
    if (base + 0 < NN) row_off[base + 0] = excl;
    if (base + 1 < NN) row_off[base + 1] = excl + v0;
    if (base + 2 < NN) row_off[base + 2] = excl + v0 + v1;
    if (base + 3 < NN) row_off[base + 3] = excl + v0 + v1 + v2;
}

__global__ void k_scan2(int* __restrict__ bsum) {
    __shared__ int lds[128];
    int t = threadIdx.x;
    int v = (t < NB1) ? bsum[t] : 0;
    lds[t] = v;
    __syncthreads();
    for (int off = 1; off < 128; off <<= 1) {
        int x = (t >= off) ? lds[t - off] : 0;
        __syncthreads();
        lds[t] += x;
        __syncthreads();
    }
    if (t < NB1) bsum[t] = lds[t] - v;  // exclusive
}

__global__ void k_scan3(int* __restrict__ row_off, const int* __restrict__ bsum) {
    int v = blockIdx.x * 256 + threadIdx.x;
    if (v < NN) {
        row_off[v] = row_off[v] + bsum[v >> 10];
    } else if (v == NN) {
        row_off[NN] = NE;
    }
}

// Per-bucket LDS scatter -> coalesced csr write.
__global__ __launch_bounds__(256) void k_phaseB(const unsigned* __restrict__ staging,
                                                const int* __restrict__ bcnt,
                                                const int* __restrict__ row_off,
                                                int* __restrict__ csr) {
    __shared__ int cur[256];
    __shared__ int buf[8192];
    const int b = blockIdx.x;
    const int node0 = b << 8;
    const int nlocal = min(256, NN - node0);
    const int base = row_off[node0];
    const int len = row_off[min(node0 + 256, NN)] - base;
    const int t = threadIdx.x;
    if (t < nlocal) cur[t] = row_off[node0 + t] - base;
    __syncthreads();
    for (int k = 0; k < KSUB; k++) {
        int cnt = min(bcnt[(b * KSUB + k) * CNT_PAD], CAPSUB);
        const unsigned* seg = staging + (size_t)b * (KSUB * CAPSUB) + k * CAPSUB;
        for (int i = t; i < cnt; i += 256) {
            unsigned p = seg[i];
            int s = (int)(p & 0x1FFFFu);
            int dl = (int)(p >> 17);
            int pos = atomicAdd(&cur[dl], 1);
            if (pos < 8192) buf[pos] = s;
        }
    }
    __syncthreads();
    for (int i = t; i < len; i += 256) csr[base + i] = buf[i];
}

// ---------------- GEMM: H[n,:] = dinv[n] * (X[n,:] @ W) ----------------
template <int C>
__global__ __launch_bounds__(256, 2) void k_gemm(const float* __restrict__ X,
                                                 const float* __restrict__ W,
                                                 const float* __restrict__ dinv,
                                                 float* __restrict__ H) {
    constexpr int K = 128, R = 32;
    constexpr int COLG = C / 4;          // col groups (float4)
    constexpr int TR = R / (256 / COLG); // rows per thread: 4 (C=128), 2 (C=64)
    __shared__ float ws[K * C];
    __shared__ float xs[R * K];
    const int tid = threadIdx.x;
    for (int i = tid; i < K * C / 4; i += 256)
        ((float4*)ws)[i] = ((const float4*)W)[i];
    const int cg = tid % COLG;
    const int rs = tid / COLG;
    constexpr int NTILES = NN / R;  // 3125 exactly
    for (int tile = blockIdx.x; tile < NTILES; tile += gridDim.x) {
        const int row0 = tile * R;
        __syncthreads();  // xs reuse guard (also covers ws load on iter 0)
        for (int i = tid; i < R * K / 4; i += 256)
            ((float4*)xs)[i] = ((const float4*)(X + (size_t)row0 * K))[i];
        __syncthreads();
        float4 acc[TR];
#pragma unroll
        for (int r = 0; r < TR; r++) acc[r] = make_float4(0.f, 0.f, 0.f, 0.f);
#pragma unroll 2
        for (int k0 = 0; k0 < K; k0 += 4) {
            float4 xv[TR];
#pragma unroll
            for (int r = 0; r < TR; r++)
                xv[r] = *(const float4*)&xs[(rs * TR + r) * K + k0];
#pragma unroll
            for (int kk = 0; kk < 4; kk++) {
                float4 w = *(const float4*)&ws[(k0 + kk) * C + cg * 4];
#pragma unroll
                for (int r = 0; r < TR; r++) {
                    float xr = (kk == 0) ? xv[r].x : (kk == 1) ? xv[r].y
                             : (kk == 2) ? xv[r].z : xv[r].w;
                    acc[r].x = fmaf(xr, w.x, acc[r].x);
                    acc[r].y = fmaf(xr, w.y, acc[r].y);
                    acc[r].z = fmaf(xr, w.z, acc[r].z);
                    acc[r].w = fmaf(xr, w.w, acc[r].w);
                }
            }
        }
#pragma unroll
        for (int r = 0; r < TR; r++) {
            int row = row0 + rs * TR + r;
            float dv = dinv[row];
            float4 o;
            o.x = acc[r].x * dv; o.y = acc[r].y * dv;
            o.z = acc[r].z * dv; o.w = acc[r].w * dv;
            *(float4*)&H[(size_t)row * C + cg * 4] = o;
        }
    }
}

// ---------------- Aggregation: OUT[v] = relu(dinv[v]*(sum_in H[u] + H[v]) + b) ----------------
template <int C, bool RELU>
__global__ __launch_bounds__(256) void k_agg(const float* __restrict__ H,
                                             const int* __restrict__ row_off,
                                             const int* __restrict__ csr,
                                             const float* __restrict__ dinv,
                                             const float* __restrict__ bias,
                                             float* __restrict__ OUT) {
    const int lane = threadIdx.x & 63;
    const int node = blockIdx.x * 4 + (threadIdx.x >> 6);
    if (node >= NN) return;
    const int beg = row_off[node];
    const int end = row_off[node + 1];
    if constexpr (C == 128) {
        const float2* __restrict__ Hp = (const float2*)H;
        const int c2 = lane;
        float ax = 0.f, ay = 0.f;
        int j = beg;
        for (; j + 4 <= end; j += 4) {
            int s0 = csr[j], s1 = csr[j + 1], s2 = csr[j + 2], s3 = csr[j + 3];
            float2 a = Hp[(size_t)s0 * 64 + c2];
            float2 b = Hp[(size_t)s1 * 64 + c2];
            float2 c = Hp[(size_t)s2 * 64 + c2];
            float2 d = Hp[(size_t)s3 * 64 + c2];
            ax += (a.x + b.x) + (c.x + d.x);
            ay += (a.y + b.y) + (c.y + d.y);
        }
        for (; j < end; ++j) {
            int s = csr[j];
            float2 a = Hp[(size_t)s * 64 + c2];
            ax += a.x; ay += a.y;
        }
        float2 hv = Hp[(size_t)node * 64 + c2];
        ax += hv.x; ay += hv.y;
        float dv = dinv[node];
        float2 bb = ((const float2*)bias)[c2];
        float ox = fmaf(ax, dv, bb.x);
        float oy = fmaf(ay, dv, bb.y);
        if (RELU) { ox = fmaxf(ox, 0.f); oy = fmaxf(oy, 0.f); }
        float2 o; o.x = ox; o.y = oy;
        ((float2*)OUT)[(size_t)node * 64 + c2] = o;
    } else {  // C == 64
        const int c = lane;
        float ax = 0.f;
        int j = beg;
        for (; j + 4 <= end; j += 4) {
            int s0 = csr[j], s1 = csr[j + 1], s2 = csr[j + 2], s3 = csr[j + 3];
            float a = H[(size_t)s0 * 64 + c];
            float b = H[(size_t)s1 * 64 + c];
            float c4 = H[(size_t)s2 * 64 + c];
            float d = H[(size_t)s3 * 64 + c];
            ax += (a + b) + (c4 + d);
        }
        for (; j < end; ++j) ax += H[(size_t)csr[j] * 64 + c];
        ax += H[(size_t)node * 64 + c];
        float dv = dinv[node];
        float o = fmaf(ax, dv, bias[c]);
        if (RELU) o = fmaxf(o, 0.f);
        OUT[(size_t)node * 64 + c] = o;
    }
}

extern "C" void kernel_launch(void* const* d_in, const int* in_sizes, int n_in,
                              void* d_out, int out_size, void* d_ws, size_t ws_size,
                              hipStream_t stream) {
    const float* x  = (const float*)d_in[0];
    const void*  ei = d_in[1];
    const float* W1 = (const float*)d_in[2];
    const float* b1 = (const float*)d_in[3];
    const float* W2 = (const float*)d_in[4];
    const float* b2 = (const float*)d_in[5];
    const float* W3 = (const float*)d_in[6];
    const float* b3 = (const float*)d_in[7];
    float* out = (float*)d_out;

    char* wsp = (char*)d_ws;
    size_t off = 0;
    auto alloc = [&](size_t bytes) -> void* {
        void* p = wsp + off;
        off += (bytes + 255) & ~(size_t)255;
        return p;
    };
    float* A       = (float*)alloc((size_t)NN * 128 * 4);
    float* B       = (float*)alloc((size_t)NN * 128 * 4);
    int*   deg     = (int*)alloc((size_t)NN * 4);
    float* dinv    = (float*)alloc((size_t)NN * 4);
    int*   row_off = (int*)alloc(((size_t)NN + 1) * 4);
    int*   bsum    = (int*)alloc((size_t)NB1 * 4);
    int*   csr     = (int*)alloc((size_t)NE * 4);
    int*   bcnt    = (int*)alloc((size_t)NBUK * KSUB * CNT_PAD * 4);
    int*   flag    = (int*)alloc(256);
    if (off > ws_size) return;  // workspace too small: fail loudly (wrong output)

    // staging (12.8 MB) aliases B: B is first written by k_agg1, after phaseB is done.
    unsigned* staging = (unsigned*)B;

    k_detect_i64<<<1, 256, 0, stream>>>((const unsigned*)ei, flag);
    k_init<<<(NN + 255) / 256, 256, 0, stream>>>(deg, bcnt);
    k_phaseA<<<2048, 256, 0, stream>>>(ei, flag, deg, bcnt, staging);
    k_dinv<<<(NN + 255) / 256, 256, 0, stream>>>(deg, dinv);
    k_scan1<<<NB1, 256, 0, stream>>>(deg, row_off, bsum);
    k_scan2<<<1, 128, 0, stream>>>(bsum);
    k_scan3<<<(NN + 1 + 255) / 256, 256, 0, stream>>>(row_off, bsum);
    k_phaseB<<<NBUK, 256, 0, stream>>>(staging, bcnt, row_off, csr);

    k_gemm<128><<<512, 256, 0, stream>>>(x, W1, dinv, A);
    k_agg<128, true><<<NN / 4, 256, 0, stream>>>(A, row_off, csr, dinv, b1, B);
    k_gemm<128><<<512, 256, 0, stream>>>(B, W2, dinv, A);
    k_agg<128, true><<<NN / 4, 256, 0, stream>>>(A, row_off, csr, dinv, b2, B);
    k_gemm<64><<<512, 256, 0, stream>>>(B, W3, dinv, A);
    k_agg<64, false><<<NN / 4, 256, 0, stream>>>(A, row_off, csr, dinv, b3, out);
}

// Round 3
// 499.420 us; speedup vs baseline: 1.3305x; 1.2394x over previous
//
#include <hip/hip_runtime.h>
#include <hip/hip_bf16.h>

#define NN 100000
#define NE 1600000
constexpr int NBUK = (NN + 255) / 256;      // 391 dst buckets of 256 nodes
constexpr int CH   = 4096;                  // edges per chunk
constexpr int EPT  = CH / 256;              // 16 edges per thread
constexpr int NCHK = (NE + CH - 1) / CH;    // 391 chunks
constexpr int LCNT = NBUK * NCHK;           // 152,881 counters
constexpr int SCB  = (LCNT + 1023) / 1024;  // 150 scan blocks

// ---------------- edge dtype detection ----------------
// int64 edge data (values < 2^32) => every odd 32-bit word of the buffer is 0.
__global__ void k_detect_i64(const unsigned* __restrict__ ei, int* __restrict__ flag) {
    __shared__ int any_nz;
    if (threadIdx.x == 0) any_nz = 0;
    __syncthreads();
    int nz = 0;
    for (int i = threadIdx.x; i < 2048; i += 256)
        if (ei[2 * i + 1] != 0u) nz = 1;
    if (nz) atomicExch(&any_nz, 1);
    __syncthreads();
    if (threadIdx.x == 0) *flag = (any_nz == 0) ? 1 : 0;
}

__device__ __forceinline__ int edge_at(const void* ei, int is64, long long idx) {
    if (is64) return (int)((const long long*)ei)[idx];
    return ((const int*)ei)[idx];
}

// ---------------- CSR build: pass 1, per-chunk LDS bucket histogram ----------------
__global__ __launch_bounds__(256) void k_count(const void* __restrict__ ei,
                                               const int* __restrict__ flag,
                                               int* __restrict__ counts) {
    __shared__ int cnt[NBUK];
    const int t = threadIdx.x, blk = blockIdx.x;
    for (int i = t; i < NBUK; i += 256) cnt[i] = 0;
    __syncthreads();
    const int is64 = *flag;
    const int e0 = blk * CH;
    const int elim = min(NE, e0 + CH);
#pragma unroll
    for (int j = 0; j < EPT; j++) {
        int e = e0 + j * 256 + t;
        if (e < elim) {
            int s = edge_at(ei, is64, e);
            int d = edge_at(ei, is64, (long long)NE + e);
            if ((unsigned)s < NN && (unsigned)d < NN) atomicAdd(&cnt[d >> 8], 1);
        }
    }
    __syncthreads();
    for (int i = t; i < NBUK; i += 256) counts[(size_t)i * NCHK + blk] = cnt[i];
}

// ---------------- exclusive scan of counts[LCNT] (in place) ----------------
__global__ void k_scan1v(int* __restrict__ data, int* __restrict__ bsum) {
    __shared__ int lds[256];
    int t = threadIdx.x, b = blockIdx.x;
    int base = b * 1024 + t * 4;
    int v0 = (base + 0 < LCNT) ? data[base + 0] : 0;
    int v1 = (base + 1 < LCNT) ? data[base + 1] : 0;
    int v2 = (base + 2 < LCNT) ? data[base + 2] : 0;
    int v3 = (base + 3 < LCNT) ? data[base + 3] : 0;
    lds[t] = v0 + v1 + v2 + v3;
    __syncthreads();
    for (int off = 1; off < 256; off <<= 1) {
        int x = (t >= off) ? lds[t - off] : 0;
        __syncthreads();
        lds[t] += x;
        __syncthreads();
    }
    int excl = (t > 0) ? lds[t - 1] : 0;
    if (t == 255) bsum[b] = lds[255];
    if (base + 0 < LCNT) data[base + 0] = excl;
    if (base + 1 < LCNT) data[base + 1] = excl + v0;
    if (base + 2 < LCNT) data[base + 2] = excl + v0 + v1;
    if (base + 3 < LCNT) data[base + 3] = excl + v0 + v1 + v2;
}

__global__ void k_scan2v(int* __restrict__ bsum) {
    __shared__ int lds[256];
    int t = threadIdx.x;
    int v = (t < SCB) ? bsum[t] : 0;
    lds[t] = v;
    __syncthreads();
    for (int off = 1; off < 256; off <<= 1) {
        int x = (t >= off) ? lds[t - off] : 0;
        __syncthreads();
        lds[t] += x;
        __syncthreads();
    }
    if (t < SCB) bsum[t] = lds[t] - v;  // exclusive
    if (t == SCB - 1) bsum[SCB] = lds[t];  // total valid edges
}

__global__ void k_scan3v(int* __restrict__ data, const int* __restrict__ bsum) {
    int i = blockIdx.x * 256 + threadIdx.x;
    if (i < LCNT) data[i] += bsum[i >> 10];
    else if (i == LCNT) data[LCNT] = bsum[SCB];
}

// ---------------- CSR build: pass 2, chunk -> LDS bucket-sort -> reserved slots ----------------
__global__ __launch_bounds__(256) void k_scatter2(const void* __restrict__ ei,
                                                  const int* __restrict__ flag,
                                                  const int* __restrict__ scanned,
                                                  unsigned* __restrict__ staging) {
    __shared__ int cnt[512], excl[512], cur[512], gbase[512];
    __shared__ unsigned lbuf[CH];
    __shared__ unsigned short lbkt[CH];
    const int t = threadIdx.x, blk = blockIdx.x;
    cnt[t] = 0; cnt[t + 256] = 0;
    __syncthreads();
    const int is64 = *flag;
    const int e0 = blk * CH;
    const int elim = min(NE, e0 + CH);
    unsigned recs[EPT];
    int bkts[EPT];
#pragma unroll
    for (int j = 0; j < EPT; j++) {
        int e = e0 + j * 256 + t;
        int bk = -1; unsigned rc = 0;
        if (e < elim) {
            int s = edge_at(ei, is64, e);
            int d = edge_at(ei, is64, (long long)NE + e);
            if ((unsigned)s < NN && (unsigned)d < NN) {
                bk = d >> 8;
                rc = (unsigned)s | ((unsigned)(d & 255) << 17);
                atomicAdd(&cnt[bk], 1);
            }
        }
        recs[j] = rc; bkts[j] = bk;
    }
    __syncthreads();
    // inclusive Hillis-Steele over 512 (2 elems/thread), then convert to exclusive
    excl[t] = cnt[t]; excl[t + 256] = cnt[t + 256];
    __syncthreads();
    for (int off = 1; off < 512; off <<= 1) {
        int a0 = (t >= off) ? excl[t - off] : 0;
        int a1 = (t + 256 >= off) ? excl[t + 256 - off] : 0;
        __syncthreads();
        excl[t] += a0; excl[t + 256] += a1;
        __syncthreads();
    }
    int i0 = excl[t] - cnt[t], i1 = excl[t + 256] - cnt[t + 256];
    excl[t] = i0; excl[t + 256] = i1;
    cur[t] = i0; cur[t + 256] = i1;
    // load this chunk's reserved global base per bucket
    for (int b = t; b < NBUK; b += 256) gbase[b] = scanned[(size_t)b * NCHK + blk];
    __syncthreads();
    // LDS bucket-sort
#pragma unroll
    for (int j = 0; j < EPT; j++) {
        if (bkts[j] >= 0) {
            int pos = atomicAdd(&cur[bkts[j]], 1);
            lbuf[pos] = recs[j];
            lbkt[pos] = (unsigned short)bkts[j];
        }
    }
    __syncthreads();
    const int tot = excl[NBUK];  // cnt[NBUK..511]==0 -> exclusive at NBUK == total
    for (int i = t; i < tot; i += 256) {
        int b = lbkt[i];
        staging[(size_t)gbase[b] + (i - excl[b])] = lbuf[i];
    }
}

// ---------------- CSR build: pass 3, per-bucket deg/row_off/dinv + sorted csr ----------------
__global__ __launch_bounds__(256) void k_phaseB2(const unsigned* __restrict__ staging,
                                                 const int* __restrict__ scanned,
                                                 float* __restrict__ dinv,
                                                 int* __restrict__ row_off,
                                                 int* __restrict__ csr) {
    __shared__ int cnt[256], excl[256], cur[256];
    __shared__ int buf[8192];
    const int t = threadIdx.x, b = blockIdx.x;
    const int node0 = b << 8;
    const int nlocal = min(256, NN - node0);
    const int seg_beg = scanned[(size_t)b * NCHK];
    const size_t nxt = (size_t)(b + 1) * NCHK;
    const int seg_end = scanned[nxt > (size_t)LCNT ? (size_t)LCNT : nxt];
    const int len = min(seg_end - seg_beg, 8192);
    cnt[t] = 0;
    __syncthreads();
    for (int i = t; i < len; i += 256) {
        unsigned r = staging[seg_beg + i];
        atomicAdd(&cnt[r >> 17], 1);
    }
    __syncthreads();
    excl[t] = cnt[t];
    __syncthreads();
    for (int off = 1; off < 256; off <<= 1) {
        int x = (t >= off) ? excl[t - off] : 0;
        __syncthreads();
        excl[t] += x;
        __syncthreads();
    }
    int ex = excl[t] - cnt[t];  // exclusive (own-slot read/write only)
    excl[t] = ex;
    cur[t] = ex;
    if (t < nlocal) {
        row_off[node0 + t] = seg_beg + ex;
        dinv[node0 + t] = rsqrtf((float)(cnt[t] + 1));  // +1 self loop
    }
    if (b == NBUK - 1 && t == 0) row_off[NN] = seg_end;
    __syncthreads();
    for (int i = t; i < len; i += 256) {
        unsigned r = staging[seg_beg + i];
        int pos = atomicAdd(&cur[r >> 17], 1);
        buf[pos] = (int)(r & 0x1FFFFu);
    }
    __syncthreads();
    for (int i = t; i < len; i += 256) csr[seg_beg + i] = buf[i];
}

// ---------------- GEMM: H[n,:] = dinv[n] * (X[n,:] @ W) ----------------
template <int C>
__global__ __launch_bounds__(256, 2) void k_gemm(const float* __restrict__ X,
                                                 const float* __restrict__ W,
                                                 const float* __restrict__ dinv,
                                                 float* __restrict__ H) {
    constexpr int K = 128, R = 32;
    constexpr int COLG = C / 4;          // col groups (float4)
    constexpr int TR = R / (256 / COLG); // rows per thread: 4 (C=128), 2 (C=64)
    __shared__ float ws[K * C];
    __shared__ float xs[R * K];
    const int tid = threadIdx.x;
    for (int i = tid; i < K * C / 4; i += 256)
        ((float4*)ws)[i] = ((const float4*)W)[i];
    const int cg = tid % COLG;
    const int rs = tid / COLG;
    constexpr int NTILES = NN / R;  // 3125 exactly
    for (int tile = blockIdx.x; tile < NTILES; tile += gridDim.x) {
        const int row0 = tile * R;
        __syncthreads();  // xs reuse guard (also covers ws load on iter 0)
        for (int i = tid; i < R * K / 4; i += 256)
            ((float4*)xs)[i] = ((const float4*)(X + (size_t)row0 * K))[i];
        __syncthreads();
        float4 acc[TR];
#pragma unroll
        for (int r = 0; r < TR; r++) acc[r] = make_float4(0.f, 0.f, 0.f, 0.f);
#pragma unroll 2
        for (int k0 = 0; k0 < K; k0 += 4) {
            float4 xv[TR];
#pragma unroll
            for (int r = 0; r < TR; r++)
                xv[r] = *(const float4*)&xs[(rs * TR + r) * K + k0];
#pragma unroll
            for (int kk = 0; kk < 4; kk++) {
                float4 w = *(const float4*)&ws[(k0 + kk) * C + cg * 4];
#pragma unroll
                for (int r = 0; r < TR; r++) {
                    float xr = (kk == 0) ? xv[r].x : (kk == 1) ? xv[r].y
                             : (kk == 2) ? xv[r].z : xv[r].w;
                    acc[r].x = fmaf(xr, w.x, acc[r].x);
                    acc[r].y = fmaf(xr, w.y, acc[r].y);
                    acc[r].z = fmaf(xr, w.z, acc[r].z);
                    acc[r].w = fmaf(xr, w.w, acc[r].w);
                }
            }
        }
#pragma unroll
        for (int r = 0; r < TR; r++) {
            int row = row0 + rs * TR + r;
            float dv = dinv[row];
            float4 o;
            o.x = acc[r].x * dv; o.y = acc[r].y * dv;
            o.z = acc[r].z * dv; o.w = acc[r].w * dv;
            *(float4*)&H[(size_t)row * C + cg * 4] = o;
        }
    }
}

// ---------------- Aggregation: OUT[v] = relu(dinv[v]*(sum_in H[u] + H[v]) + b) ----------------
template <int C, bool RELU>
__global__ __launch_bounds__(256) void k_agg(const float* __restrict__ H,
                                             const int* __restrict__ row_off,
                                             const int* __restrict__ csr,
                                             const float* __restrict__ dinv,
                                             const float* __restrict__ bias,
                                             float* __restrict__ OUT) {
    const int lane = threadIdx.x & 63;
    const int node = blockIdx.x * 4 + (threadIdx.x >> 6);
    if (node >= NN) return;
    const int beg = row_off[node];
    const int end = row_off[node + 1];
    if constexpr (C == 128) {
        const float2* __restrict__ Hp = (const float2*)H;
        const int c2 = lane;
        float ax = 0.f, ay = 0.f;
        int j = beg;
        for (; j + 4 <= end; j += 4) {
            int s0 = csr[j], s1 = csr[j + 1], s2 = csr[j + 2], s3 = csr[j + 3];
            float2 a = Hp[(size_t)s0 * 64 + c2];
            float2 b = Hp[(size_t)s1 * 64 + c2];
            float2 c = Hp[(size_t)s2 * 64 + c2];
            float2 d = Hp[(size_t)s3 * 64 + c2];
            ax += (a.x + b.x) + (c.x + d.x);
            ay += (a.y + b.y) + (c.y + d.y);
        }
        for (; j < end; ++j) {
            int s = csr[j];
            float2 a = Hp[(size_t)s * 64 + c2];
            ax += a.x; ay += a.y;
        }
        float2 hv = Hp[(size_t)node * 64 + c2];
        ax += hv.x; ay += hv.y;
        float dv = dinv[node];
        float2 bb = ((const float2*)bias)[c2];
        float ox = fmaf(ax, dv, bb.x);
        float oy = fmaf(ay, dv, bb.y);
        if (RELU) { ox = fmaxf(ox, 0.f); oy = fmaxf(oy, 0.f); }
        float2 o; o.x = ox; o.y = oy;
        ((float2*)OUT)[(size_t)node * 64 + c2] = o;
    } else {  // C == 64
        const int c = lane;
        float ax = 0.f;
        int j = beg;
        for (; j + 4 <= end; j += 4) {
            int s0 = csr[j], s1 = csr[j + 1], s2 = csr[j + 2], s3 = csr[j + 3];
            float a = H[(size_t)s0 * 64 + c];
            float b = H[(size_t)s1 * 64 + c];
            float c4 = H[(size_t)s2 * 64 + c];
            float d = H[(size_t)s3 * 64 + c];
            ax += (a + b) + (c4 + d);
        }
        for (; j < end; ++j) ax += H[(size_t)csr[j] * 64 + c];
        ax += H[(size_t)node * 64 + c];
        float dv = dinv[node];
        float o = fmaf(ax, dv, bias[c]);
        if (RELU) o = fmaxf(o, 0.f);
        OUT[(size_t)node * 64 + c] = o;
    }
}

extern "C" void kernel_launch(void* const* d_in, const int* in_sizes, int n_in,
                              void* d_out, int out_size, void* d_ws, size_t ws_size,
                              hipStream_t stream) {
    const float* x  = (const float*)d_in[0];
    const void*  ei = d_in[1];
    const float* W1 = (const float*)d_in[2];
    const float* b1 = (const float*)d_in[3];
    const float* W2 = (const float*)d_in[4];
    const float* b2 = (const float*)d_in[5];
    const float* W3 = (const float*)d_in[6];
    const float* b3 = (const float*)d_in[7];
    float* out = (float*)d_out;

    char* wsp = (char*)d_ws;
    size_t off = 0;
    auto alloc = [&](size_t bytes) -> void* {
        void* p = wsp + off;
        off += (bytes + 255) & ~(size_t)255;
        return p;
    };
    float* A       = (float*)alloc((size_t)NN * 128 * 4);
    float* B       = (float*)alloc((size_t)NN * 128 * 4);
    float* dinv    = (float*)alloc((size_t)NN * 4);
    int*   row_off = (int*)alloc(((size_t)NN + 1) * 4);
    int*   counts  = (int*)alloc(((size_t)LCNT + 1) * 4);
    int*   bsum    = (int*)alloc(((size_t)SCB + 1) * 4);
    int*   csr     = (int*)alloc((size_t)NE * 4);
    int*   flag    = (int*)alloc(256);
    if (off > ws_size) return;  // workspace too small: fail loudly (wrong output)

    // staging (6.4 MB) aliases B: B is first written by agg layer 1, after phaseB2.
    unsigned* staging = (unsigned*)B;

    k_detect_i64<<<1, 256, 0, stream>>>((const unsigned*)ei, flag);
    k_count<<<NCHK, 256, 0, stream>>>(ei, flag, counts);
    k_scan1v<<<SCB, 256, 0, stream>>>(counts, bsum);
    k_scan2v<<<1, 256, 0, stream>>>(bsum);
    k_scan3v<<<(LCNT + 1 + 255) / 256, 256, 0, stream>>>(counts, bsum);
    k_scatter2<<<NCHK, 256, 0, stream>>>(ei, flag, counts, staging);
    k_phaseB2<<<NBUK, 256, 0, stream>>>(staging, counts, dinv, row_off, csr);

    k_gemm<128><<<512, 256, 0, stream>>>(x, W1, dinv, A);
    k_agg<128, true><<<NN / 4, 256, 0, stream>>>(A, row_off, csr, dinv, b1, B);
    k_gemm<128><<<512, 256, 0, stream>>>(B, W2, dinv, A);
    k_agg<128, true><<<NN / 4, 256, 0, stream>>>(A, row_off, csr, dinv, b2, B);
    k_gemm<64><<<512, 256, 0, stream>>>(B, W3, dinv, A);
    k_agg<64, false><<<NN / 4, 256, 0, stream>>>(A, row_off, csr, dinv, b3, out);
}